// Round 14
// baseline (76.065 us; speedup 1.0000x reference)
//
#include <hip/hip_runtime.h>

// ---------------------------------------------------------------------------
// Joint network: y = relu(f@W1t^T + g@W1p^T + (b1t+b1p)) @ W2^T + b2
// N=32768, K1=1344 (1024 f + 320 g), J=512, KOUT=29. fp32 in/out, bf16 MFMA.
// R14: m201-faithful 8-phase-style interleave on the R13 skeleton.
//      Tile 128x512, BK=64, 8 waves (wave tile 64x128). Per K-tile: 4 phases
//      of 16 MFMA, each staging ONE 16-KB B-quarter of tile t+1 via 2 gls.
//      Counted vmcnt: VMCNT(8)@q1, VMCNT(4)@q3 — never 0 in steady state.
//      A: issue 4xf32x4 @q1, cvt + XOR'd b128 ds_write @q3 (dep-exact wait).
// ---------------------------------------------------------------------------

typedef float  f32x4  __attribute__((ext_vector_type(4)));
typedef short  s16x8  __attribute__((ext_vector_type(8)));   // 8 bf16

#define N_ROWS   32768
#define KOUT     29

// Wc layout: [tile21][ks2][jhalf2][kc4][j256][8] — 16-KB gls quarters.
#define WC_ELEMS   (21 * 2 * 2 * 4 * 256 * 8)   // 688128 bf16
#define W2C_ELEMS  (64 * 32 * 8)                // 16384 bf16: [jc][ko32][8]

#define VMCNT(n)   asm volatile("s_waitcnt vmcnt(" #n ")" ::: "memory")
#define LGKM0()    asm volatile("s_waitcnt lgkmcnt(0)" ::: "memory")
#define SBAR()     __builtin_amdgcn_s_barrier()
#define PRIO(n)    __builtin_amdgcn_s_setprio(n)

typedef const __attribute__((address_space(1))) unsigned int* gp_t;
typedef __attribute__((address_space(3))) unsigned int* lp_t;

static __device__ __forceinline__ void gls16(const void* g, void* l) {
  __builtin_amdgcn_global_load_lds((gp_t)g, (lp_t)l, 16, 0, 0);
}

static __device__ __forceinline__ unsigned short f2bf(float x) {
  union { float f; unsigned u; } v; v.f = x;
  unsigned r = v.u + 0x7fffu + ((v.u >> 16) & 1u);   // RNE
  return (unsigned short)(r >> 16);
}

// ---------------------------------------------------------------------------
__global__ __launch_bounds__(512) void prep_kernel(
    const float* __restrict__ W1t, const float* __restrict__ b1t,
    const float* __restrict__ W1p, const float* __restrict__ b1p,
    const float* __restrict__ W2,  const float* __restrict__ b2,
    unsigned short* __restrict__ Wc, unsigned short* __restrict__ W2c,
    float* __restrict__ bc, float* __restrict__ b2c) {
  int idx = blockIdx.x * 512 + threadIdx.x;
  if (idx < WC_ELEMS) {
    int e  = idx & 7;
    int j2 = (idx >> 3) & 255;
    int kc = (idx >> 11) & 3;
    int jh = (idx >> 13) & 1;
    int ks = (idx >> 14) & 1;
    int t  = idx >> 15;
    int j  = jh * 256 + j2;
    int c  = t * 64 + ks * 32 + kc * 8 + e;
    float v = (c < 1024) ? W1t[j * 1024 + c] : W1p[j * 320 + (c - 1024)];
    Wc[idx] = f2bf(v);
  }
  if (idx < W2C_ELEMS) {
    int e  = idx & 7;
    int ko = (idx >> 3) & 31;
    int jc = idx >> 8;
    int j  = jc * 8 + e;
    float v = (ko < KOUT) ? W2[ko * 512 + j] : 0.0f;
    W2c[idx] = f2bf(v);
  }
  if (idx < 512) bc[idx]  = b1t[idx] + b1p[idx];
  if (idx < 32)  b2c[idx] = (idx < KOUT) ? b2[idx] : 0.0f;
}

// ---------------------------------------------------------------------------
// 256 blocks x 512 threads (8 waves, 1 block/CU). Block tile 128 x 512.
// Wave w: wm=w>>2 rows wm*64+[0,64), wn=w&3 cols wn*128+[0,128).
// LDS: A dbuf [2][8kc][128row][8] @0          (32 KB, XOR-swizzled)
//      B dbuf [2][4quarter][16KB] @32768      (128 KB, gls-linear quarters)
//      phase2 h-chunk [16pl][128r][8] @0      (32 KB, aliases A)
// Total 163840 B = 160 KiB.
// ---------------------------------------------------------------------------
__global__ __launch_bounds__(512, 2) void joint_kernel(
    const float* __restrict__ f, const float* __restrict__ g,
    const unsigned short* __restrict__ Wc, const unsigned short* __restrict__ W2c,
    const float* __restrict__ bc, const float* __restrict__ b2c,
    float* __restrict__ out) {
  __shared__ __align__(16) char smem[163840];

  const int tid = threadIdx.x;
  const int l   = tid & 63;
  const int w   = tid >> 6;          // wave 0..7
  const int wm  = w >> 2;            // 0..1 (rows wm*64)
  const int wn  = w & 3;             // 0..3 (cols wn*128)
  const int m0  = blockIdx.x * 128;

  const int kcg = l >> 4;            // 0..3
  const int lc  = l & 15;

  // A staging map (R13-verified): row = tid>>2 (128), q = tid&3; thread
  // stages k=[q*16,q*16+16) of its row per tile -> kc planes 2q, 2q+1.
  const int rowW = tid >> 2;
  const int q    = tid & 3;
  const char* fAth = (const char*)f + (size_t)(m0 + rowW) * 4096 + q * 64;
  const char* gAth = (const char*)g + (size_t)(m0 + rowW) * 1280 + q * 64;
  const unsigned awr0 = (unsigned)((2 * q)     * 2048 + ((rowW * 16) ^ ((2 * q)     << 5)));
  const unsigned awr1 = (unsigned)((2 * q + 1) * 2048 + ((rowW * 16) ^ ((2 * q + 1) << 5)));

  // A fragment read bases (ks0: planes kcg; ks1: planes kcg+4)
  const unsigned a0base = (unsigned)(kcg * 2048 + wm * 1024 + ((lc * 16) ^ (kcg << 5)));
  const unsigned a1base = (unsigned)((kcg + 4) * 2048 + wm * 1024 + ((lc * 16) ^ ((kcg + 4) << 5)));
  // B fragment read base, relative to a 64-KB B buffer:
  // quarter = ks*2 + (wn>>1); within: kc*4096 + qj*16, qj=(wn&1)*128+ni*16+lc
  const unsigned b_rd = (unsigned)((wn >> 1) * 16384 + kcg * 4096 +
                                   (wn & 1) * 2048 + lc * 16);

  f32x4 acc[4][8];
#pragma unroll
  for (int mi = 0; mi < 4; mi++)
#pragma unroll
    for (int ni = 0; ni < 8; ni++) acc[mi][ni] = (f32x4)(0.0f);

  f32x4 pN0, pN1, pN2, pN3;          // A prefetch (16 VGPR, issue q1 -> write q3)

  // Stage one 16-KB B quarter QS of tile T into buffer DB (2 x gls16).
#define GLSQ(T, QS, DB) {                                                   \
    const char* bs_ = (const char*)Wc + (size_t)(T) * 65536 +               \
                      (QS) * 16384 + tid * 16;                              \
    char* bd_ = smem + 32768 + (size_t)(DB) * 65536 + (QS) * 16384 + tid * 16; \
    gls16(bs_,         bd_);                                                \
    gls16(bs_ + 8192,  bd_ + 8192);                                         \
  }

#define A_ISSUE(ASRC) {                                                     \
    pN0 = *(const f32x4*)(ASRC);                                            \
    pN1 = *(const f32x4*)((ASRC) + 16);                                     \
    pN2 = *(const f32x4*)((ASRC) + 32);                                     \
    pN3 = *(const f32x4*)((ASRC) + 48);                                     \
  }

#define WRA(AB) {                                                           \
    s16x8 h0_, h1_;                                                         \
    h0_[0] = (short)f2bf(pN0[0]); h0_[1] = (short)f2bf(pN0[1]);             \
    h0_[2] = (short)f2bf(pN0[2]); h0_[3] = (short)f2bf(pN0[3]);             \
    h0_[4] = (short)f2bf(pN1[0]); h0_[5] = (short)f2bf(pN1[1]);             \
    h0_[6] = (short)f2bf(pN1[2]); h0_[7] = (short)f2bf(pN1[3]);             \
    h1_[0] = (short)f2bf(pN2[0]); h1_[1] = (short)f2bf(pN2[1]);             \
    h1_[2] = (short)f2bf(pN2[2]); h1_[3] = (short)f2bf(pN2[3]);             \
    h1_[4] = (short)f2bf(pN3[0]); h1_[5] = (short)f2bf(pN3[1]);             \
    h1_[6] = (short)f2bf(pN3[2]); h1_[7] = (short)f2bf(pN3[3]);             \
    *(s16x8*)(smem + (AB) * 16384 + awr0) = h0_;                            \
    *(s16x8*)(smem + (AB) * 16384 + awr1) = h1_;                            \
  }

#define MFMA16(NOFF)                                                        \
    PRIO(1);                                                                \
    _Pragma("unroll")                                                       \
    for (int mi = 0; mi < 4; mi++)                                          \
      _Pragma("unroll")                                                     \
      for (int ni = 0; ni < 4; ni++)                                        \
        acc[mi][(NOFF) + ni] = __builtin_amdgcn_mfma_f32_16x16x32_bf16(     \
            af_[mi], bq_[ni], acc[mi][(NOFF) + ni], 0, 0, 0);               \
    PRIO(0);

  // One K-tile = 4 barrier-paired phases of 16 MFMA each.
#define K_TILE(T, P, G, AI, ASRC, VMID, VEND) {                             \
    s16x8 af_[4]; s16x8 bq_[4];                                             \
    const unsigned ab_ = (P) * 16384u;                                      \
    const unsigned bb_ = 32768u + (P) * 65536u;                             \
    /* q0: ks0, ni 0-3 */                                                   \
    _Pragma("unroll")                                                       \
    for (int mi = 0; mi < 4; mi++)                                          \
      af_[mi] = *(const s16x8*)(smem + ab_ + a0base + mi * 256);            \
    _Pragma("unroll")                                                       \
    for (int ni = 0; ni < 4; ni++)                                          \
      bq_[ni] = *(const s16x8*)(smem + bb_ + b_rd + ni * 256);              \
    if (G) { GLSQ((T) + 1, 0, (P) ^ 1); }                                   \
    SBAR();                                                                 \
    MFMA16(0);                                                              \
    SBAR();                                                                 \
    /* q1: ks0, ni 4-7 */                                                   \
    _Pragma("unroll")                                                       \
    for (int ni = 0; ni < 4; ni++)                                          \
      bq_[ni] = *(const s16x8*)(smem + bb_ + b_rd + (4 + ni) * 256);        \
    if (G)  { GLSQ((T) + 1, 1, (P) ^ 1); }                                  \
    if (AI) { A_ISSUE(ASRC); }                                              \
    VMID;                                                                   \
    SBAR();                                                                 \
    MFMA16(4);                                                              \
    SBAR();                                                                 \
    /* q2: ks1, ni 0-3 */                                                   \
    _Pragma("unroll")                                                       \
    for (int mi = 0; mi < 4; mi++)                                          \
      af_[mi] = *(const s16x8*)(smem + ab_ + a1base + mi * 256);            \
    _Pragma("unroll")                                                       \
    for (int ni = 0; ni < 4; ni++)                                          \
      bq_[ni] = *(const s16x8*)(smem + bb_ + 32768u + b_rd + ni * 256);     \
    if (G) { GLSQ((T) + 1, 2, (P) ^ 1); }                                   \
    SBAR();                                                                 \
    MFMA16(0);                                                              \
    SBAR();                                                                 \
    /* q3: ks1, ni 4-7 */                                                   \
    _Pragma("unroll")                                                       \
    for (int ni = 0; ni < 4; ni++)                                          \
      bq_[ni] = *(const s16x8*)(smem + bb_ + 32768u + b_rd + (4 + ni) * 256); \
    if (G)  { GLSQ((T) + 1, 3, (P) ^ 1); }                                  \
    if (AI) { WRA((P) ^ 1); }  /* implicit exact vmcnt for A regs */        \
    VEND;                                                                   \
    LGKM0();                   /* drain A ds_writes before barrier */       \
    SBAR();                                                                 \
    MFMA16(4);                                                              \
    SBAR();                                                                 \
  }

  // ---- prologue: stage tile 0 (B quarters x4 + A) fully, drain, bar ----
  GLSQ(0, 0, 0); GLSQ(0, 1, 0); GLSQ(0, 2, 0); GLSQ(0, 3, 0);
  A_ISSUE(fAth);
  WRA(0);                      // implicit wait drains all gls + A loads
  VMCNT(0);
  LGKM0();
  SBAR();

  // ---- K loop: tiles 0..17 (paired), 18..20 explicit ----
  for (int T = 0; T < 18; T += 2) {
    const char* s0 = (T + 1 < 16) ? fAth + (size_t)(T + 1) * 256
                                  : gAth + (size_t)(T - 15) * 256;
    const char* s1 = (T + 2 < 16) ? fAth + (size_t)(T + 2) * 256
                                  : gAth + (size_t)(T - 14) * 256;
    K_TILE(T,     0, 1, 1, s0, VMCNT(8), VMCNT(4));
    K_TILE(T + 1, 1, 1, 1, s1, VMCNT(8), VMCNT(4));
  }
  K_TILE(18, 0, 1, 1, gAth + 3 * 256, VMCNT(8), VMCNT(4));
  K_TILE(19, 1, 1, 1, gAth + 4 * 256, VMCNT(8), VMCNT(4));
  K_TILE(20, 0, 0, 0, fAth,           VMCNT(0), VMCNT(0));

  // ---- phase 2 (verified structure): y = relu(h+bias) @ W2^T + b2 ----
  // Chunk p: cols [p*128,(p+1)*128), written by waves wn==p (wm 0,1).
  // Consumers: wave w owns y rows w*16..w*16+15, both ko-tiles.
  float bias[8];
#pragma unroll
  for (int ni = 0; ni < 8; ni++) bias[ni] = bc[wn * 128 + ni * 16 + lc];

  f32x4 acc2a = (f32x4)(0.0f);
  f32x4 acc2b = (f32x4)(0.0f);
  const unsigned h_rdrow = (unsigned)((w * 16 + lc) * 16);

#pragma unroll
  for (int p = 0; p < 4; p++) {
    __syncthreads();                 // h chunk region free
    if (wn == p) {
#pragma unroll
      for (int ni = 0; ni < 8; ni++) {
        const int jrel  = ni * 16 + lc;          // 0..127
        const int plane = jrel >> 3;             // 0..15
        const unsigned wswz = (unsigned)((plane & 3) << 5);
#pragma unroll
        for (int mi = 0; mi < 4; mi++)
#pragma unroll
          for (int r = 0; r < 4; r++) {
            float v = fmaxf(acc[mi][ni][r] + bias[ni], 0.0f);
            const unsigned rowh = (unsigned)(wm * 64 + mi * 16 + kcg * 4 + r);
            *(unsigned short*)(smem + plane * 2048 +
                ((rowh * 16 + (jrel & 7) * 2) ^ wswz)) = f2bf(v);
          }
      }
    }
    __syncthreads();
#pragma unroll
    for (int ks2 = 0; ks2 < 4; ks2++) {
      const int plane = ks2 * 4 + kcg;
      s16x8 hf = *(const s16x8*)(smem + plane * 2048 +
                                 (h_rdrow ^ ((unsigned)(plane & 3) << 5)));
      s16x8 w0 = *(const s16x8*)((const char*)W2c + (p * 16 + plane) * 512 + lc * 16);
      s16x8 w1 = *(const s16x8*)((const char*)W2c + (p * 16 + plane) * 512 + (16 + lc) * 16);
      acc2a = __builtin_amdgcn_mfma_f32_16x16x32_bf16(hf, w0, acc2a, 0, 0, 0);
      acc2b = __builtin_amdgcn_mfma_f32_16x16x32_bf16(hf, w1, acc2b, 0, 0, 0);
    }
  }

  // ---- epilogue: +b2, store (29 of 32 cols) ----
  {
    const float bb0 = b2c[lc];
    const float bb1 = b2c[16 + lc];
    const int orow0 = m0 + w * 16 + kcg * 4;
#pragma unroll
    for (int r = 0; r < 4; r++) {
      const size_t row = (size_t)(orow0 + r);
      out[row * KOUT + lc] = acc2a[r] + bb0;
      if (lc < KOUT - 16) out[row * KOUT + 16 + lc] = acc2b[r] + bb1;
    }
  }

#undef GLSQ
#undef A_ISSUE
#undef WRA
#undef MFMA16
#undef K_TILE
}

// ---------------------------------------------------------------------------
extern "C" void kernel_launch(void* const* d_in, const int* in_sizes, int n_in,
                              void* d_out, int out_size, void* d_ws, size_t ws_size,
                              hipStream_t stream) {
  const float* f   = (const float*)d_in[0];
  const float* g   = (const float*)d_in[1];
  const float* W1t = (const float*)d_in[2];
  const float* b1t = (const float*)d_in[3];
  const float* W1p = (const float*)d_in[4];
  const float* b1p = (const float*)d_in[5];
  const float* W2  = (const float*)d_in[6];
  const float* b2  = (const float*)d_in[7];
  float* out = (float*)d_out;

  unsigned short* Wc  = (unsigned short*)d_ws;
  unsigned short* W2c = Wc + WC_ELEMS;
  float* bcp  = (float*)(W2c + W2C_ELEMS);
  float* b2cp = bcp + 512;

  prep_kernel<<<WC_ELEMS / 512, 512, 0, stream>>>(W1t, b1t, W1p, b1p, W2, b2,
                                                  Wc, W2c, bcp, b2cp);
  joint_kernel<<<N_ROWS / 128, 512, 0, stream>>>(f, g, Wc, W2c, bcp, b2cp, out);
}